// Round 16
// baseline (168.974 us; speedup 1.0000x reference)
//
#include <hip/hip_runtime.h>

typedef _Float16 f16;
typedef _Float16 f16x8 __attribute__((ext_vector_type(8)));
typedef _Float16 f16x4 __attribute__((ext_vector_type(4)));
typedef __fp16 fp16x2 __attribute__((ext_vector_type(2)));
typedef float f32x4 __attribute__((ext_vector_type(4)));

#define HID 2048
#define NH 32
#define NKV 8
#define HD 64
#define SEQ 2048
#define NB 2

__device__ __forceinline__ void gload_lds16(const void* g, void* l) {
  __builtin_amdgcn_global_load_lds((const __attribute__((address_space(1))) void*)g,
                                   (__attribute__((address_space(3))) void*)l, 16, 0, 0);
}

__device__ __forceinline__ uint cvt_pk_f16(float a, float b) {
  auto v = __builtin_amdgcn_cvt_pkrtz(a, b);
  uint u;
  __builtin_memcpy(&u, &v, 4);
  return u;
}

__device__ __forceinline__ float fdot2_ones(uint pk, float acc) {
  fp16x2 a;
  __builtin_memcpy(&a, &pk, 4);
  fp16x2 ones = {(__fp16)1.0f, (__fp16)1.0f};
  return __builtin_amdgcn_fdot2(a, ones, acc, false);
}

// raw v_exp_f32 (2^x): single trans-op; domain |s|<=11.6 or -1e30 (masked ->
// underflow to 0) needs no denormal fixup.
__device__ __forceinline__ float fast_exp2(float x) {
  float r;
  asm("v_exp_f32 %0, %1" : "=v"(r) : "v"(x));
  return r;
}

// ---------------- fused f32 -> f16 convert of all 5 tensors ----------------
__global__ __launch_bounds__(256) void cvt_all(const float* __restrict__ X,
                                               const float* __restrict__ Wq,
                                               const float* __restrict__ Wk,
                                               const float* __restrict__ Wv,
                                               const float* __restrict__ Wo,
                                               f16* __restrict__ Xb, f16* __restrict__ Wqb,
                                               f16* __restrict__ Wkb, f16* __restrict__ Wvb,
                                               f16* __restrict__ Wob) {
  long i = (long)blockIdx.x * 256 + threadIdx.x;
  const float* s; f16* d; long o;
  if (i < 2097152)      { s = X;  d = Xb;  o = i; }
  else if (i < 3145728) { s = Wq; d = Wqb; o = i - 2097152; }
  else if (i < 3407872) { s = Wk; d = Wkb; o = i - 3145728; }
  else if (i < 3670016) { s = Wv; d = Wvb; o = i - 3407872; }
  else                  { s = Wo; d = Wob; o = i - 3670016; }
  float4 v = ((const float4*)s)[o];
  f16x4 ov = { (f16)v.x, (f16)v.y, (f16)v.z, (f16)v.w };
  ((f16x4*)d)[o] = ov;
}

// ---------------- GEMM 256x256, 4-phase interleave (QKV projection) --------
// BM=BN=256, BK=64, 8 waves (2M x 4N), per-wave 128x64 output, 1 block/CU.
// LDS layout identical to the PROVEN 128^2 kernel (128B rows, slot^(row&7),
// measured 0 conflicts in R9). The R9 failure was pipe serialization, not
// layout: monolithic read-then-MFMA alternated the LDS and MFMA pipes.
// Fix: 4 quadrant-phases per K-step {ds_reads -> 16 MFMA} with sched_barrier
// fences so phase q+1's reads overlap phase q's MFMA drain. Staging bursts at
// iter end into the just-freed buffer; consumed 2 iterations (~4800 cyc)
// later -> HBM latency fully covered. 2 barriers + counted vmcnt(8) per iter.
__global__ __launch_bounds__(512, 2) void gemm256(const f16* __restrict__ A,
                                                  const f16* __restrict__ Bm,
                                                  f16* __restrict__ C0, f16* __restrict__ C1,
                                                  int M, int N, int K,
                                                  int n_split, int ldc0, int ldc1) {
  __shared__ f16 As[2][256 * 64];
  __shared__ f16 Bs[2][256 * 64];
  const int t = threadIdx.x, lane = t & 63, w = t >> 6;
  const int wr = w >> 2, wc = w & 3;
  const int g = lane >> 4, lr = lane & 15;

  const int nwg = gridDim.x * gridDim.y;
  const int orig = blockIdx.y * gridDim.x + blockIdx.x;
  const int wg = (orig & 7) * (nwg >> 3) + (orig >> 3);
  const int m0 = (wg / gridDim.x) * 256;
  const int n0 = (wg % gridDim.x) * 256;

  f32x4 acc[8][4] = {};
  const int nkt = K / 64;

  auto stage = [&](int buf, int kt) {
    const int k0 = kt * 64;
#pragma unroll
    for (int i = 0; i < 4; ++i) {
      int c = w * 4 + i;                      // 32 chunks x 8 rows = 256 rows
      int o = c * 1024 + lane * 16;
      int row = o >> 7;
      int ss = ((o >> 4) & 7) ^ (row & 7);
      gload_lds16((const char*)A + ((size_t)(m0 + row) * K + k0) * 2 + ss * 16,
                  (char*)(&As[buf][0]) + c * 1024);
      gload_lds16((const char*)Bm + ((size_t)(n0 + row) * K + k0) * 2 + ss * 16,
                  (char*)(&Bs[buf][0]) + c * 1024);
    }
  };

  stage(0, 0);
  stage(1, 1);
  for (int kt = 0; kt < nkt; ++kt) {
    const int cur = kt & 1;
    if (kt + 1 < nkt) asm volatile("s_waitcnt vmcnt(8)" ::: "memory");
    else              asm volatile("s_waitcnt vmcnt(0)" ::: "memory");
    __builtin_amdgcn_s_barrier();
    __builtin_amdgcn_sched_barrier(0);

    const char* Ab = (const char*)(&As[cur][0]);
    const char* Bb = (const char*)(&Bs[cur][0]);
    f16x8 af[2][4], bf[2][4];

    // ---- phase 1: read af(mf0-3) + bf(nf0-1); MFMA quadrant (mf0-3, nf0-1)
#pragma unroll
    for (int ks = 0; ks < 2; ++ks)
#pragma unroll
      for (int mf = 0; mf < 4; ++mf) {
        int row = wr * 128 + mf * 16 + lr;
        af[ks][mf] = *(const f16x8*)(Ab + row * 128 + (((g + 4 * ks) ^ (row & 7)) * 16));
      }
#pragma unroll
    for (int ks = 0; ks < 2; ++ks)
#pragma unroll
      for (int nf = 0; nf < 2; ++nf) {
        int row = wc * 64 + nf * 16 + lr;
        bf[ks][nf] = *(const f16x8*)(Bb + row * 128 + (((g + 4 * ks) ^ (row & 7)) * 16));
      }
    __builtin_amdgcn_s_setprio(1);
#pragma unroll
    for (int ks = 0; ks < 2; ++ks)
#pragma unroll
      for (int mf = 0; mf < 4; ++mf)
#pragma unroll
        for (int nf = 0; nf < 2; ++nf)
          acc[mf][nf] = __builtin_amdgcn_mfma_f32_16x16x32_f16(af[ks][mf], bf[ks][nf], acc[mf][nf], 0, 0, 0);
    __builtin_amdgcn_s_setprio(0);
    __builtin_amdgcn_sched_barrier(0);

    // ---- phase 2: read bf(nf2-3); MFMA quadrant (mf0-3, nf2-3)
#pragma unroll
    for (int ks = 0; ks < 2; ++ks)
#pragma unroll
      for (int nf = 2; nf < 4; ++nf) {
        int row = wc * 64 + nf * 16 + lr;
        bf[ks][nf] = *(const f16x8*)(Bb + row * 128 + (((g + 4 * ks) ^ (row & 7)) * 16));
      }
    __builtin_amdgcn_s_setprio(1);
#pragma unroll
    for (int ks = 0; ks < 2; ++ks)
#pragma unroll
      for (int mf = 0; mf < 4; ++mf)
#pragma unroll
        for (int nf = 2; nf < 4; ++nf)
          acc[mf][nf] = __builtin_amdgcn_mfma_f32_16x16x32_f16(af[ks][mf], bf[ks][nf], acc[mf][nf], 0, 0, 0);
    __builtin_amdgcn_s_setprio(0);
    __builtin_amdgcn_sched_barrier(0);

    // ---- phase 3: read af(mf4-7); MFMA quadrant (mf4-7, nf0-1)
#pragma unroll
    for (int ks = 0; ks < 2; ++ks)
#pragma unroll
      for (int mf = 0; mf < 4; ++mf) {
        int row = wr * 128 + (mf + 4) * 16 + lr;
        af[ks][mf] = *(const f16x8*)(Ab + row * 128 + (((g + 4 * ks) ^ (row & 7)) * 16));
      }
    __builtin_amdgcn_s_setprio(1);
#pragma unroll
    for (int ks = 0; ks < 2; ++ks)
#pragma unroll
      for (int mf = 0; mf < 4; ++mf)
#pragma unroll
        for (int nf = 0; nf < 2; ++nf)
          acc[mf + 4][nf] = __builtin_amdgcn_mfma_f32_16x16x32_f16(af[ks][mf], bf[ks][nf], acc[mf + 4][nf], 0, 0, 0);
    __builtin_amdgcn_s_setprio(0);
    __builtin_amdgcn_sched_barrier(0);

    // ---- phase 4: MFMA quadrant (mf4-7, nf2-3), no reads
    __builtin_amdgcn_s_setprio(1);
#pragma unroll
    for (int ks = 0; ks < 2; ++ks)
#pragma unroll
      for (int mf = 0; mf < 4; ++mf)
#pragma unroll
        for (int nf = 2; nf < 4; ++nf)
          acc[mf + 4][nf] = __builtin_amdgcn_mfma_f32_16x16x32_f16(af[ks][mf], bf[ks][nf], acc[mf + 4][nf], 0, 0, 0);
    __builtin_amdgcn_s_setprio(0);
    __builtin_amdgcn_sched_barrier(0);

    // WAR: all waves done reading buf cur -> refill it with tile kt+2
    __builtin_amdgcn_s_barrier();
    __builtin_amdgcn_sched_barrier(0);
    if (kt + 2 < nkt) stage(cur, kt + 2);
  }

  f16* Cp; int ldc, nb;
  if (n0 < n_split) { Cp = C0; ldc = ldc0; nb = n0; }
  else              { Cp = C1; ldc = ldc1; nb = n0 - n_split; }
#pragma unroll
  for (int mf = 0; mf < 8; ++mf)
#pragma unroll
    for (int nf = 0; nf < 4; ++nf)
#pragma unroll
      for (int r = 0; r < 4; ++r) {
        int mm = m0 + wr * 128 + mf * 16 + g * 4 + r;
        int nn = nb + wc * 64 + nf * 16 + lr;
        Cp[(size_t)mm * ldc + nn] = (f16)acc[mf][nf][r];
      }
}

// ---------------- GEMM 128x128: counted-vmcnt 2-barrier pipeline (815 TF) --
template <typename CT>
__global__ __launch_bounds__(256) void gemm_bt(const f16* __restrict__ A,
                                               const f16* __restrict__ Bm,
                                               CT* __restrict__ C0, CT* __restrict__ C1,
                                               int M, int N, int K,
                                               int n_split, int ldc0, int ldc1) {
  __shared__ f16 As[2][128 * 64];
  __shared__ f16 Bs[2][128 * 64];
  const int t = threadIdx.x;
  const int lane = t & 63;
  const int w = t >> 6;
  const int wr = w >> 1, wc = w & 1;
  const int g = lane >> 4;
  const int lr = lane & 15;

  const int nwg = gridDim.x * gridDim.y;
  const int orig = blockIdx.y * gridDim.x + blockIdx.x;
  const int wg = (orig & 7) * (nwg >> 3) + (orig >> 3);
  const int m0 = (wg / gridDim.x) * 128;
  const int n0 = (wg % gridDim.x) * 128;

  f32x4 acc[4][4] = {};

  const int nkt = K / 64;

  auto stage = [&](int buf, int kt) {
    const int k0 = kt * 64;
#pragma unroll
    for (int i = 0; i < 4; ++i) {
      int c = w * 4 + i;
      int o = c * 1024 + lane * 16;
      int row = o >> 7;
      int ss = ((o >> 4) & 7) ^ (row & 7);
      const char* srcA = (const char*)A + ((size_t)(m0 + row) * K + k0) * 2 + ss * 16;
      gload_lds16(srcA, (char*)(&As[buf][0]) + c * 1024);
      const char* srcB = (const char*)Bm + ((size_t)(n0 + row) * K + k0) * 2 + ss * 16;
      gload_lds16(srcB, (char*)(&Bs[buf][0]) + c * 1024);
    }
  };

  stage(0, 0);
  if (nkt > 1) stage(1, 1);
  for (int kt = 0; kt < nkt; ++kt) {
    const int cur = kt & 1;
    if (kt + 1 < nkt) asm volatile("s_waitcnt vmcnt(8)" ::: "memory");
    else              asm volatile("s_waitcnt vmcnt(0)" ::: "memory");
    __builtin_amdgcn_s_barrier();
    __builtin_amdgcn_sched_barrier(0);

    f16x8 af[2][4], bf[2][4];
#pragma unroll
    for (int ks = 0; ks < 2; ++ks)
#pragma unroll
      for (int mf = 0; mf < 4; ++mf) {
        int row = wr * 64 + mf * 16 + lr;
        int slot = (g + 4 * ks) ^ (row & 7);
        af[ks][mf] = *(const f16x8*)((const char*)(&As[cur][0]) + row * 128 + slot * 16);
      }
#pragma unroll
    for (int ks = 0; ks < 2; ++ks)
#pragma unroll
      for (int nf = 0; nf < 4; ++nf) {
        int row = wc * 64 + nf * 16 + lr;
        int slot = (g + 4 * ks) ^ (row & 7);
        bf[ks][nf] = *(const f16x8*)((const char*)(&Bs[cur][0]) + row * 128 + slot * 16);
      }
    asm volatile("s_waitcnt lgkmcnt(0)" ::: "memory");
    __builtin_amdgcn_sched_barrier(0);
    __builtin_amdgcn_s_barrier();

    if (kt + 2 < nkt) stage(cur, kt + 2);

    __builtin_amdgcn_s_setprio(1);
#pragma unroll
    for (int ks = 0; ks < 2; ++ks)
#pragma unroll
      for (int mf = 0; mf < 4; ++mf)
#pragma unroll
        for (int nf = 0; nf < 4; ++nf)
          acc[mf][nf] = __builtin_amdgcn_mfma_f32_16x16x32_f16(af[ks][mf], bf[ks][nf], acc[mf][nf], 0, 0, 0);
    __builtin_amdgcn_s_setprio(0);
  }

  CT* Cp; int ldc, nb;
  if (n0 < n_split) { Cp = C0; ldc = ldc0; nb = n0; }
  else              { Cp = C1; ldc = ldc1; nb = n0 - n_split; }
#pragma unroll
  for (int mf = 0; mf < 4; ++mf)
#pragma unroll
    for (int nf = 0; nf < 4; ++nf)
#pragma unroll
      for (int r = 0; r < 4; ++r) {
        int mm = m0 + wr * 64 + mf * 16 + g * 4 + r;
        int nn = nb + wc * 64 + nf * 16 + lr;
        Cp[(size_t)mm * ldc + nn] = (CT)acc[mf][nf][r];
      }
}

// ---------------- V transpose + K RMSNorm ----------------
__global__ __launch_bounds__(256) void vtrans(f16* __restrict__ KV,
                                              f16* __restrict__ VT,
                                              const float* __restrict__ kw) {
  __shared__ f16 tile[64][72];
  int t = threadIdx.x;
  int st = blockIdx.x, hk = blockIdx.y, b = blockIdx.z;

#pragma unroll
  for (int p = 0; p < 2; ++p) {
    int idx = p * 256 + t;
    int s = idx >> 3, c8 = (idx & 7) * 8;
    f16* kp = KV + (size_t)(b * SEQ + st * 64 + s) * 1024 + hk * 64 + c8;
    f16x8 kv = *(const f16x8*)kp;
    float ss = 0.f;
#pragma unroll
    for (int j = 0; j < 8; ++j) { float x = (float)kv[j]; ss += x * x; }
    ss += __shfl_xor(ss, 1); ss += __shfl_xor(ss, 2); ss += __shfl_xor(ss, 4);
    float sc = rsqrtf(ss * (1.0f / 64.0f) + 1e-6f);
    f16x8 on;
#pragma unroll
    for (int j = 0; j < 8; ++j) on[j] = (f16)((float)kv[j] * sc * kw[c8 + j]);
    *(f16x8*)kp = on;
  }

#pragma unroll
  for (int p = 0; p < 2; ++p) {
    int idx = p * 256 + t;
    int s = idx >> 3, c8 = (idx & 7) * 8;
    f16x8 v = *(const f16x8*)(KV + (size_t)(b * SEQ + st * 64 + s) * 1024 + 512 + hk * 64 + c8);
    *(f16x8*)(&tile[s][c8]) = v;
  }
  __syncthreads();
#pragma unroll
  for (int p = 0; p < 2; ++p) {
    int idx = p * 256 + t;
    int d = idx >> 3, s8 = (idx & 7) * 8;
    f16x8 ov;
#pragma unroll
    for (int j = 0; j < 8; ++j) {
      int pos = s8 + j;
      int k = (pos & 32) | (((pos >> 2) & 1) << 4) | (((pos >> 4) & 1) << 3)
            | (((pos >> 3) & 1) << 2) | (pos & 3);
      ov[j] = tile[k][d];
    }
    *(f16x8*)(VT + ((size_t)((b * NKV + hk) * 64) + d) * SEQ + st * 64 + s8) = ov;
  }
}

// ---------------- causal GQA flash attention (+ fused Q RMSNorm) ----------
__global__ __launch_bounds__(512) void attn(const f16* __restrict__ Q,
                                            const f16* __restrict__ KV,
                                            const f16* __restrict__ VT,
                                            f16* __restrict__ AO,
                                            const float* __restrict__ qw) {
  __shared__ f16 Ks[3][64 * 64];
  __shared__ f16 Vs[3][64 * 64];
  const int t = threadIdx.x, lane = t & 63, w = t >> 6;
  const int g = lane >> 4, lr = lane & 15;
  const int col = blockIdx.x;
  const int qt = 31 - blockIdx.y;
  const int b = col & 1;
  const int h = 2 * (col >> 1) + (w >> 2);
  const int rg = w & 3;
  const int hk = h >> 2;
  const int q0 = qt * 64;

  const size_t qrow = (size_t)(b * SEQ + q0 + rg * 16 + lr);
  f16x8 qf[2];
  qf[0] = *(const f16x8*)(Q + qrow * HID + h * 64 + g * 8);
  qf[1] = *(const f16x8*)(Q + qrow * HID + h * 64 + g * 8 + 32);

  {
    float ss = 0.f;
#pragma unroll
    for (int i = 0; i < 2; ++i)
#pragma unroll
      for (int j = 0; j < 8; ++j) { float x = (float)qf[i][j]; ss += x * x; }
    ss += __shfl_xor(ss, 16); ss += __shfl_xor(ss, 32);
    float sc = rsqrtf(ss * (1.0f / 64.0f) + 1e-6f) * (0.125f * 1.44269504f);
    const float4* qw4 = (const float4*)qw;
    float4 w0 = qw4[2 * g], w1 = qw4[2 * g + 1];
    float4 w2 = qw4[2 * g + 8], w3 = qw4[2 * g + 9];
    qf[0][0] = (f16)((float)qf[0][0] * sc * w0.x);
    qf[0][1] = (f16)((float)qf[0][1] * sc * w0.y);
    qf[0][2] = (f16)((float)qf[0][2] * sc * w0.z);
    qf[0][3] = (f16)((float)qf[0][3] * sc * w0.w);
    qf[0][4] = (f16)((float)qf[0][4] * sc * w1.x);
    qf[0][5] = (f16)((float)qf[0][5] * sc * w1.y);
    qf[0][6] = (f16)((float)qf[0][6] * sc * w1.z);
    qf[0][7] = (f16)((float)qf[0][7] * sc * w1.w);
    qf[1][0] = (f16)((float)qf[1][0] * sc * w2.x);
    qf[1][1] = (f16)((float)qf[1][1] * sc * w2.y);
    qf[1][2] = (f16)((float)qf[1][2] * sc * w2.z);
    qf[1][3] = (f16)((float)qf[1][3] * sc * w2.w);
    qf[1][4] = (f16)((float)qf[1][4] * sc * w3.x);
    qf[1][5] = (f16)((float)qf[1][5] * sc * w3.y);
    qf[1][6] = (f16)((float)qf[1][6] * sc * w3.z);
    qf[1][7] = (f16)((float)qf[1][7] * sc * w3.w);
  }

  int koff[2][4], voff[2][4];
#pragma unroll
  for (int ks = 0; ks < 2; ++ks)
#pragma unroll
    for (int nf = 0; nf < 4; ++nf) {
      int row = nf * 16 + lr;
      koff[ks][nf] = row * 128 + (((g + 4 * ks) ^ (row & 7)) * 16);
    }
#pragma unroll
  for (int m = 0; m < 2; ++m)
#pragma unroll
    for (int df = 0; df < 4; ++df) {
      int row = df * 16 + lr;
      voff[m][df] = row * 128 + (((4 * m + g) ^ (row & 7)) * 16);
    }

  f32x4 oacc[4] = {};
  float psum0 = 0.0f, psum1 = 0.0f;

  const int nkt = qt + 1;

  auto stage = [&](int buf, int kt2) {
    int o = w * 1024 + lane * 16;
    int row = o >> 7;
    int ss = ((o >> 4) & 7) ^ (row & 7);
    gload_lds16((const char*)KV + ((size_t)(b * SEQ + kt2 * 64 + row) * 1024 + hk * 64) * 2 + ss * 16,
                (char*)(&Ks[buf][0]) + w * 1024);
    gload_lds16((const char*)VT + (((size_t)((b * NKV + hk) * 64) + row) * SEQ + kt2 * 64) * 2 + ss * 16,
                (char*)(&Vs[buf][0]) + w * 1024);
  };

  stage(0, 0);
  if (nkt > 1) stage(1, 1);
  int cur = 0;
  for (int kt = 0; kt < nkt; ++kt) {
    if (kt + 1 < nkt) asm volatile("s_waitcnt vmcnt(2)" ::: "memory");
    else              asm volatile("s_waitcnt vmcnt(0)" ::: "memory");
    __builtin_amdgcn_s_barrier();
    asm volatile("" ::: "memory");

    if (kt + 2 < nkt) {
      int nb = cur + 2; if (nb >= 3) nb -= 3;
      stage(nb, kt + 2);
    }

    const char* Kb = (const char*)(&Ks[cur][0]);
    const char* Vb = (const char*)(&Vs[cur][0]);

    f32x4 sacc[4] = {};
#pragma unroll
    for (int ks = 0; ks < 2; ++ks) {
      __builtin_amdgcn_s_setprio(1);
#pragma unroll
      for (int nf = 0; nf < 4; ++nf) {
        f16x8 kf = *(const f16x8*)(Kb + koff[ks][nf]);
        sacc[nf] = __builtin_amdgcn_mfma_f32_16x16x32_f16(kf, qf[ks], sacc[nf], 0, 0, 0);
      }
      __builtin_amdgcn_s_setprio(0);
    }

    if (kt == qt) {
      int qq = q0 + rg * 16 + lr;
#pragma unroll
      for (int nf = 0; nf < 4; ++nf) {
        int kvb = kt * 64 + nf * 16 + g * 4;
#pragma unroll
        for (int r = 0; r < 4; ++r)
          if (kvb + r > qq) sacc[nf][r] = -1e30f;
      }
    }

    uint pk[8];
#pragma unroll
    for (int nf = 0; nf < 4; ++nf) {
      float p0 = fast_exp2(sacc[nf][0]);
      float p1 = fast_exp2(sacc[nf][1]);
      float p2 = fast_exp2(sacc[nf][2]);
      float p3 = fast_exp2(sacc[nf][3]);
      pk[2 * nf]     = cvt_pk_f16(p0, p1);
      pk[2 * nf + 1] = cvt_pk_f16(p2, p3);
      psum0 = fdot2_ones(pk[2 * nf], psum0);
      psum1 = fdot2_ones(pk[2 * nf + 1], psum1);
    }

#pragma unroll
    for (int m = 0; m < 2; ++m) {
      union { uint u[4]; f16x8 v; } pu;
      pu.u[0] = pk[4 * m];     pu.u[1] = pk[4 * m + 1];
      pu.u[2] = pk[4 * m + 2]; pu.u[3] = pk[4 * m + 3];
      __builtin_amdgcn_s_setprio(1);
#pragma unroll
      for (int df = 0; df < 4; ++df) {
        f16x8 vf = *(const f16x8*)(Vb + voff[m][df]);
        oacc[df] = __builtin_amdgcn_mfma_f32_16x16x32_f16(pu.v, vf, oacc[df], 0, 0, 0);
      }
      __builtin_amdgcn_s_setprio(0);
    }

    cur = (cur == 2) ? 0 : cur + 1;
  }

  float psum = psum0 + psum1;
  psum += __shfl_xor(psum, 16);
  psum += __shfl_xor(psum, 32);
  float pdiv[4];
#pragma unroll
  for (int r = 0; r < 4; ++r) pdiv[r] = 1.0f / __shfl(psum, g * 4 + r);

#pragma unroll
  for (int df = 0; df < 4; ++df)
#pragma unroll
    for (int r = 0; r < 4; ++r) {
      size_t rowg = (size_t)(b * SEQ + q0 + rg * 16 + g * 4 + r);
      AO[rowg * HID + h * 64 + df * 16 + lr] = (f16)(oacc[df][r] * pdiv[r]);
    }
}

// ---------------- launch ----------------
extern "C" void kernel_launch(void* const* d_in, const int* in_sizes, int n_in,
                              void* d_out, int out_size, void* d_ws, size_t ws_size,
                              hipStream_t stream) {
  const float* X  = (const float*)d_in[0];
  const float* Wq = (const float*)d_in[1];
  const float* Wk = (const float*)d_in[2];
  const float* Wv = (const float*)d_in[3];
  const float* Wo = (const float*)d_in[4];
  const float* qw = (const float*)d_in[5];
  const float* kw = (const float*)d_in[6];

  char* ws = (char*)d_ws;
  f16* Xb   = (f16*)(ws + 0);           // 4096 x 2048
  f16* Wqkv = (f16*)(ws + 16777216);    // 3072 x 2048 (Wq | Wk | Wv rows)
  f16* Wob  = (f16*)(ws + 29360128);    // 2048 x 2048
  f16* Qb   = (f16*)(ws + 37748736);    // 4096 x 2048
  f16* KVb  = (f16*)(ws + 54525952);    // 4096 x 1024 (K cols 0..511, V 512..1023)
  f16* VTb  = (f16*)(ws + 62914560);    // [2][8][64][2048] permuted V^T
  f16* AOb  = (f16*)(ws + 67108864);    // 4096 x 2048
  float* OUT = (float*)d_out;

  cvt_all<<<18432, 256, 0, stream>>>(X, Wq, Wk, Wv, Wo,
                                     Xb, Wqkv, Wqkv + 2048 * 2048, Wqkv + 2560 * 2048, Wob);

  // fused QKV projection: 256^2 4-phase interleave (grid 12x16 = 192, %8==0)
  gemm256<<<dim3(12, 16), 512, 0, stream>>>(Xb, Wqkv, Qb, KVb,
                                            4096, 3072, 2048, 2048, 2048, 1024);

  vtrans<<<dim3(32, 8, 2), 256, 0, stream>>>(KVb, VTb, kw);
  attn<<<dim3(32, 32, 1), 512, 0, stream>>>(Qb, KVb, VTb, AOb, qw);

  gemm_bt<float><<<dim3(16, 32), 256, 0, stream>>>(AOb, Wob, OUT, OUT,
                                                   4096, 2048, 2048, 2048, 2048, 2048);
}

// Round 17
// 165.389 us; speedup vs baseline: 1.0217x; 1.0217x over previous
//
#include <hip/hip_runtime.h>

typedef _Float16 f16;
typedef _Float16 f16x8 __attribute__((ext_vector_type(8)));
typedef _Float16 f16x4 __attribute__((ext_vector_type(4)));
typedef __fp16 fp16x2 __attribute__((ext_vector_type(2)));
typedef float f32x4 __attribute__((ext_vector_type(4)));

#define HID 2048
#define NH 32
#define NKV 8
#define HD 64
#define SEQ 2048
#define NB 2

__device__ __forceinline__ void gload_lds16(const void* g, void* l) {
  __builtin_amdgcn_global_load_lds((const __attribute__((address_space(1))) void*)g,
                                   (__attribute__((address_space(3))) void*)l, 16, 0, 0);
}

__device__ __forceinline__ uint cvt_pk_f16(float a, float b) {
  auto v = __builtin_amdgcn_cvt_pkrtz(a, b);
  uint u;
  __builtin_memcpy(&u, &v, 4);
  return u;
}

__device__ __forceinline__ float fdot2_ones(uint pk, float acc) {
  fp16x2 a;
  __builtin_memcpy(&a, &pk, 4);
  fp16x2 ones = {(__fp16)1.0f, (__fp16)1.0f};
  return __builtin_amdgcn_fdot2(a, ones, acc, false);
}

// raw v_exp_f32 (2^x): single trans-op; domain |s|<=11.6 or -1e30 (masked ->
// underflow to 0) needs no denormal fixup.
__device__ __forceinline__ float fast_exp2(float x) {
  float r;
  asm("v_exp_f32 %0, %1" : "=v"(r) : "v"(x));
  return r;
}

// ---------------- fused f32 -> f16 convert of all 5 tensors ----------------
__global__ __launch_bounds__(256) void cvt_all(const float* __restrict__ X,
                                               const float* __restrict__ Wq,
                                               const float* __restrict__ Wk,
                                               const float* __restrict__ Wv,
                                               const float* __restrict__ Wo,
                                               f16* __restrict__ Xb, f16* __restrict__ Wqb,
                                               f16* __restrict__ Wkb, f16* __restrict__ Wvb,
                                               f16* __restrict__ Wob) {
  long i = (long)blockIdx.x * 256 + threadIdx.x;
  const float* s; f16* d; long o;
  if (i < 2097152)      { s = X;  d = Xb;  o = i; }
  else if (i < 3145728) { s = Wq; d = Wqb; o = i - 2097152; }
  else if (i < 3407872) { s = Wk; d = Wkb; o = i - 3145728; }
  else if (i < 3670016) { s = Wv; d = Wvb; o = i - 3407872; }
  else                  { s = Wo; d = Wob; o = i - 3670016; }
  float4 v = ((const float4*)s)[o];
  f16x4 ov = { (f16)v.x, (f16)v.y, (f16)v.z, (f16)v.w };
  ((f16x4*)d)[o] = ov;
}

// ---------------- GEMM 128x128: counted-vmcnt 2-barrier pipeline (815 TF) --
template <typename CT>
__global__ __launch_bounds__(256) void gemm_bt(const f16* __restrict__ A,
                                               const f16* __restrict__ Bm,
                                               CT* __restrict__ C0, CT* __restrict__ C1,
                                               int M, int N, int K,
                                               int n_split, int ldc0, int ldc1) {
  __shared__ f16 As[2][128 * 64];
  __shared__ f16 Bs[2][128 * 64];
  const int t = threadIdx.x;
  const int lane = t & 63;
  const int w = t >> 6;
  const int wr = w >> 1, wc = w & 1;
  const int g = lane >> 4;
  const int lr = lane & 15;

  const int nwg = gridDim.x * gridDim.y;
  const int orig = blockIdx.y * gridDim.x + blockIdx.x;
  const int wg = (orig & 7) * (nwg >> 3) + (orig >> 3);
  const int m0 = (wg / gridDim.x) * 128;
  const int n0 = (wg % gridDim.x) * 128;

  f32x4 acc[4][4] = {};

  const int nkt = K / 64;

  auto stage = [&](int buf, int kt) {
    const int k0 = kt * 64;
#pragma unroll
    for (int i = 0; i < 4; ++i) {
      int c = w * 4 + i;
      int o = c * 1024 + lane * 16;
      int row = o >> 7;
      int ss = ((o >> 4) & 7) ^ (row & 7);
      const char* srcA = (const char*)A + ((size_t)(m0 + row) * K + k0) * 2 + ss * 16;
      gload_lds16(srcA, (char*)(&As[buf][0]) + c * 1024);
      const char* srcB = (const char*)Bm + ((size_t)(n0 + row) * K + k0) * 2 + ss * 16;
      gload_lds16(srcB, (char*)(&Bs[buf][0]) + c * 1024);
    }
  };

  stage(0, 0);
  if (nkt > 1) stage(1, 1);
  for (int kt = 0; kt < nkt; ++kt) {
    const int cur = kt & 1;
    if (kt + 1 < nkt) asm volatile("s_waitcnt vmcnt(8)" ::: "memory");
    else              asm volatile("s_waitcnt vmcnt(0)" ::: "memory");
    __builtin_amdgcn_s_barrier();
    __builtin_amdgcn_sched_barrier(0);

    f16x8 af[2][4], bf[2][4];
#pragma unroll
    for (int ks = 0; ks < 2; ++ks)
#pragma unroll
      for (int mf = 0; mf < 4; ++mf) {
        int row = wr * 64 + mf * 16 + lr;
        int slot = (g + 4 * ks) ^ (row & 7);
        af[ks][mf] = *(const f16x8*)((const char*)(&As[cur][0]) + row * 128 + slot * 16);
      }
#pragma unroll
    for (int ks = 0; ks < 2; ++ks)
#pragma unroll
      for (int nf = 0; nf < 4; ++nf) {
        int row = wc * 64 + nf * 16 + lr;
        int slot = (g + 4 * ks) ^ (row & 7);
        bf[ks][nf] = *(const f16x8*)((const char*)(&Bs[cur][0]) + row * 128 + slot * 16);
      }
    asm volatile("s_waitcnt lgkmcnt(0)" ::: "memory");
    __builtin_amdgcn_sched_barrier(0);
    __builtin_amdgcn_s_barrier();

    if (kt + 2 < nkt) stage(cur, kt + 2);

    __builtin_amdgcn_s_setprio(1);
#pragma unroll
    for (int ks = 0; ks < 2; ++ks)
#pragma unroll
      for (int mf = 0; mf < 4; ++mf)
#pragma unroll
        for (int nf = 0; nf < 4; ++nf)
          acc[mf][nf] = __builtin_amdgcn_mfma_f32_16x16x32_f16(af[ks][mf], bf[ks][nf], acc[mf][nf], 0, 0, 0);
    __builtin_amdgcn_s_setprio(0);
  }

  CT* Cp; int ldc, nb;
  if (n0 < n_split) { Cp = C0; ldc = ldc0; nb = n0; }
  else              { Cp = C1; ldc = ldc1; nb = n0 - n_split; }
#pragma unroll
  for (int mf = 0; mf < 4; ++mf)
#pragma unroll
    for (int nf = 0; nf < 4; ++nf)
#pragma unroll
      for (int r = 0; r < 4; ++r) {
        int mm = m0 + wr * 64 + mf * 16 + g * 4 + r;
        int nn = nb + wc * 64 + nf * 16 + lr;
        Cp[(size_t)mm * ldc + nn] = (CT)acc[mf][nf][r];
      }
}

// ---------------- V transpose + K RMSNorm ----------------
__global__ __launch_bounds__(256) void vtrans(f16* __restrict__ KV,
                                              f16* __restrict__ VT,
                                              const float* __restrict__ kw) {
  __shared__ f16 tile[64][72];
  int t = threadIdx.x;
  int st = blockIdx.x, hk = blockIdx.y, b = blockIdx.z;

#pragma unroll
  for (int p = 0; p < 2; ++p) {
    int idx = p * 256 + t;
    int s = idx >> 3, c8 = (idx & 7) * 8;
    f16* kp = KV + (size_t)(b * SEQ + st * 64 + s) * 1024 + hk * 64 + c8;
    f16x8 kv = *(const f16x8*)kp;
    float ss = 0.f;
#pragma unroll
    for (int j = 0; j < 8; ++j) { float x = (float)kv[j]; ss += x * x; }
    ss += __shfl_xor(ss, 1); ss += __shfl_xor(ss, 2); ss += __shfl_xor(ss, 4);
    float sc = rsqrtf(ss * (1.0f / 64.0f) + 1e-6f);
    f16x8 on;
#pragma unroll
    for (int j = 0; j < 8; ++j) on[j] = (f16)((float)kv[j] * sc * kw[c8 + j]);
    *(f16x8*)kp = on;
  }

#pragma unroll
  for (int p = 0; p < 2; ++p) {
    int idx = p * 256 + t;
    int s = idx >> 3, c8 = (idx & 7) * 8;
    f16x8 v = *(const f16x8*)(KV + (size_t)(b * SEQ + st * 64 + s) * 1024 + 512 + hk * 64 + c8);
    *(f16x8*)(&tile[s][c8]) = v;
  }
  __syncthreads();
#pragma unroll
  for (int p = 0; p < 2; ++p) {
    int idx = p * 256 + t;
    int d = idx >> 3, s8 = (idx & 7) * 8;
    f16x8 ov;
#pragma unroll
    for (int j = 0; j < 8; ++j) {
      int pos = s8 + j;
      int k = (pos & 32) | (((pos >> 2) & 1) << 4) | (((pos >> 4) & 1) << 3)
            | (((pos >> 3) & 1) << 2) | (pos & 3);
      ov[j] = tile[k][d];
    }
    *(f16x8*)(VT + ((size_t)((b * NKV + hk) * 64) + d) * SEQ + st * 64 + s8) = ov;
  }
}

// ---------------- causal GQA flash attention (+ fused Q RMSNorm) ----------
// R8-proven structure: KVBLK=64, 3-buffer staging with counted vmcnt(2) + raw
// barrier, swapped QK^T (P in registers), PV single-b128 via permuted VT,
// fixed-max softmax via raw v_exp_f32 (log2e folded into Q-norm), fdot2 psum,
// global LPT.
__global__ __launch_bounds__(512) void attn(const f16* __restrict__ Q,
                                            const f16* __restrict__ KV,
                                            const f16* __restrict__ VT,
                                            f16* __restrict__ AO,
                                            const float* __restrict__ qw) {
  __shared__ f16 Ks[3][64 * 64];
  __shared__ f16 Vs[3][64 * 64];
  const int t = threadIdx.x, lane = t & 63, w = t >> 6;
  const int g = lane >> 4, lr = lane & 15;
  const int col = blockIdx.x;
  const int qt = 31 - blockIdx.y;
  const int b = col & 1;
  const int h = 2 * (col >> 1) + (w >> 2);
  const int rg = w & 3;
  const int hk = h >> 2;
  const int q0 = qt * 64;

  const size_t qrow = (size_t)(b * SEQ + q0 + rg * 16 + lr);
  f16x8 qf[2];
  qf[0] = *(const f16x8*)(Q + qrow * HID + h * 64 + g * 8);
  qf[1] = *(const f16x8*)(Q + qrow * HID + h * 64 + g * 8 + 32);

  // fused Q RMSNorm; folds 1/sqrt(64) attn scale AND log2(e) for exp2 softmax
  {
    float ss = 0.f;
#pragma unroll
    for (int i = 0; i < 2; ++i)
#pragma unroll
      for (int j = 0; j < 8; ++j) { float x = (float)qf[i][j]; ss += x * x; }
    ss += __shfl_xor(ss, 16); ss += __shfl_xor(ss, 32);
    float sc = rsqrtf(ss * (1.0f / 64.0f) + 1e-6f) * (0.125f * 1.44269504f);
    const float4* qw4 = (const float4*)qw;
    float4 w0 = qw4[2 * g], w1 = qw4[2 * g + 1];
    float4 w2 = qw4[2 * g + 8], w3 = qw4[2 * g + 9];
    qf[0][0] = (f16)((float)qf[0][0] * sc * w0.x);
    qf[0][1] = (f16)((float)qf[0][1] * sc * w0.y);
    qf[0][2] = (f16)((float)qf[0][2] * sc * w0.z);
    qf[0][3] = (f16)((float)qf[0][3] * sc * w0.w);
    qf[0][4] = (f16)((float)qf[0][4] * sc * w1.x);
    qf[0][5] = (f16)((float)qf[0][5] * sc * w1.y);
    qf[0][6] = (f16)((float)qf[0][6] * sc * w1.z);
    qf[0][7] = (f16)((float)qf[0][7] * sc * w1.w);
    qf[1][0] = (f16)((float)qf[1][0] * sc * w2.x);
    qf[1][1] = (f16)((float)qf[1][1] * sc * w2.y);
    qf[1][2] = (f16)((float)qf[1][2] * sc * w2.z);
    qf[1][3] = (f16)((float)qf[1][3] * sc * w2.w);
    qf[1][4] = (f16)((float)qf[1][4] * sc * w3.x);
    qf[1][5] = (f16)((float)qf[1][5] * sc * w3.y);
    qf[1][6] = (f16)((float)qf[1][6] * sc * w3.z);
    qf[1][7] = (f16)((float)qf[1][7] * sc * w3.w);
  }

  // hoisted LDS byte offsets (loop-invariant across kv tiles)
  int koff[2][4], voff[2][4];
#pragma unroll
  for (int ks = 0; ks < 2; ++ks)
#pragma unroll
    for (int nf = 0; nf < 4; ++nf) {
      int row = nf * 16 + lr;
      koff[ks][nf] = row * 128 + (((g + 4 * ks) ^ (row & 7)) * 16);
    }
#pragma unroll
  for (int m = 0; m < 2; ++m)
#pragma unroll
    for (int df = 0; df < 4; ++df) {
      int row = df * 16 + lr;
      voff[m][df] = row * 128 + (((4 * m + g) ^ (row & 7)) * 16);
    }

  f32x4 oacc[4] = {};
  float psum0 = 0.0f, psum1 = 0.0f;

  const int nkt = qt + 1;

  auto stage = [&](int buf, int kt2) {
    int o = w * 1024 + lane * 16;
    int row = o >> 7;
    int ss = ((o >> 4) & 7) ^ (row & 7);
    gload_lds16((const char*)KV + ((size_t)(b * SEQ + kt2 * 64 + row) * 1024 + hk * 64) * 2 + ss * 16,
                (char*)(&Ks[buf][0]) + w * 1024);
    gload_lds16((const char*)VT + (((size_t)((b * NKV + hk) * 64) + row) * SEQ + kt2 * 64) * 2 + ss * 16,
                (char*)(&Vs[buf][0]) + w * 1024);
  };

  stage(0, 0);
  if (nkt > 1) stage(1, 1);
  int cur = 0;
  for (int kt = 0; kt < nkt; ++kt) {
    if (kt + 1 < nkt) asm volatile("s_waitcnt vmcnt(2)" ::: "memory");
    else              asm volatile("s_waitcnt vmcnt(0)" ::: "memory");
    __builtin_amdgcn_s_barrier();
    asm volatile("" ::: "memory");

    if (kt + 2 < nkt) {
      int nb = cur + 2; if (nb >= 3) nb -= 3;
      stage(nb, kt + 2);
    }

    const char* Kb = (const char*)(&Ks[cur][0]);
    const char* Vb = (const char*)(&Vs[cur][0]);

    // S^T = K Q^T : lane holds S[q=lr][k = nf*16 + g*4 + r] (log2-domain)
    f32x4 sacc[4] = {};
#pragma unroll
    for (int ks = 0; ks < 2; ++ks) {
      __builtin_amdgcn_s_setprio(1);
#pragma unroll
      for (int nf = 0; nf < 4; ++nf) {
        f16x8 kf = *(const f16x8*)(Kb + koff[ks][nf]);
        sacc[nf] = __builtin_amdgcn_mfma_f32_16x16x32_f16(kf, qf[ks], sacc[nf], 0, 0, 0);
      }
      __builtin_amdgcn_s_setprio(0);
    }

    if (kt == qt) {  // diagonal tile: causal mask
      int qq = q0 + rg * 16 + lr;
#pragma unroll
      for (int nf = 0; nf < 4; ++nf) {
        int kvb = kt * 64 + nf * 16 + g * 4;
#pragma unroll
        for (int r = 0; r < 4; ++r)
          if (kvb + r > qq) sacc[nf][r] = -1e30f;
      }
    }

    // P = 2^S via raw v_exp_f32; pack to f16; row-sum via dot2 on packed P
    uint pk[8];
#pragma unroll
    for (int nf = 0; nf < 4; ++nf) {
      float p0 = fast_exp2(sacc[nf][0]);
      float p1 = fast_exp2(sacc[nf][1]);
      float p2 = fast_exp2(sacc[nf][2]);
      float p3 = fast_exp2(sacc[nf][3]);
      pk[2 * nf]     = cvt_pk_f16(p0, p1);
      pk[2 * nf + 1] = cvt_pk_f16(p2, p3);
      psum0 = fdot2_ones(pk[2 * nf], psum0);
      psum1 = fdot2_ones(pk[2 * nf + 1], psum1);
    }

    // O += P V; V fragment = single b128 (layout permutation matches P's k-map)
#pragma unroll
    for (int m = 0; m < 2; ++m) {
      union { uint u[4]; f16x8 v; } pu;
      pu.u[0] = pk[4 * m];     pu.u[1] = pk[4 * m + 1];
      pu.u[2] = pk[4 * m + 2]; pu.u[3] = pk[4 * m + 3];
      __builtin_amdgcn_s_setprio(1);
#pragma unroll
      for (int df = 0; df < 4; ++df) {
        f16x8 vf = *(const f16x8*)(Vb + voff[m][df]);
        oacc[df] = __builtin_amdgcn_mfma_f32_16x16x32_f16(pu.v, vf, oacc[df], 0, 0, 0);
      }
      __builtin_amdgcn_s_setprio(0);
    }

    cur = (cur == 2) ? 0 : cur + 1;
  }

  float psum = psum0 + psum1;
  psum += __shfl_xor(psum, 16);
  psum += __shfl_xor(psum, 32);
  float pdiv[4];
#pragma unroll
  for (int r = 0; r < 4; ++r) pdiv[r] = 1.0f / __shfl(psum, g * 4 + r);

#pragma unroll
  for (int df = 0; df < 4; ++df)
#pragma unroll
    for (int r = 0; r < 4; ++r) {
      size_t rowg = (size_t)(b * SEQ + q0 + rg * 16 + g * 4 + r);
      AO[rowg * HID + h * 64 + df * 16 + lr] = (f16)(oacc[df][r] * pdiv[r]);
    }
}

// ---------------- launch ----------------
extern "C" void kernel_launch(void* const* d_in, const int* in_sizes, int n_in,
                              void* d_out, int out_size, void* d_ws, size_t ws_size,
                              hipStream_t stream) {
  const float* X  = (const float*)d_in[0];
  const float* Wq = (const float*)d_in[1];
  const float* Wk = (const float*)d_in[2];
  const float* Wv = (const float*)d_in[3];
  const float* Wo = (const float*)d_in[4];
  const float* qw = (const float*)d_in[5];
  const float* kw = (const float*)d_in[6];

  char* ws = (char*)d_ws;
  f16* Xb   = (f16*)(ws + 0);           // 4096 x 2048
  f16* Wqkv = (f16*)(ws + 16777216);    // 3072 x 2048 (Wq | Wk | Wv rows)
  f16* Wob  = (f16*)(ws + 29360128);    // 2048 x 2048
  f16* Qb   = (f16*)(ws + 37748736);    // 4096 x 2048
  f16* KVb  = (f16*)(ws + 54525952);    // 4096 x 1024 (K cols 0..511, V 512..1023)
  f16* VTb  = (f16*)(ws + 62914560);    // [2][8][64][2048] permuted V^T
  f16* AOb  = (f16*)(ws + 67108864);    // 4096 x 2048
  float* OUT = (float*)d_out;

  cvt_all<<<18432, 256, 0, stream>>>(X, Wq, Wk, Wv, Wo,
                                     Xb, Wqkv, Wqkv + 2048 * 2048, Wqkv + 2560 * 2048, Wob);

  gemm_bt<f16><<<dim3(24, 32), 256, 0, stream>>>(Xb, Wqkv, Qb, KVb,
                                                 4096, 3072, 2048, 2048, 2048, 1024);

  vtrans<<<dim3(32, 8, 2), 256, 0, stream>>>(KVb, VTb, kw);
  attn<<<dim3(32, 32, 1), 512, 0, stream>>>(Qb, KVb, VTb, AOb, qw);

  gemm_bt<float><<<dim3(16, 32), 256, 0, stream>>>(AOb, Wob, OUT, OUT,
                                                   4096, 2048, 2048, 2048, 2048, 2048);
}